// Round 1
// baseline (190.606 us; speedup 1.0000x reference)
//
#include <hip/hip_runtime.h>

#define Bn 32
#define Tn 256
#define Cn 512
#define Ln 25

__device__ __forceinline__ float tanh_fast(float x) {
    // tanh(x) = 1 - 2/(1 + e^{2x}); safe at extremes (exp->0 or inf)
    float e = __expf(x + x);
    float r = __builtin_amdgcn_rcpf(e + 1.0f);
    return fmaf(-2.0f, r, 1.0f);
}

// K1: wf[m][n] = sum_k A[m][k] * W[n][k] + bias[n]
// M=8192, N=512, K=512. Tile 128(m) x 64(n), BK=16, 256 threads, 8x4 micro.
__global__ __launch_bounds__(256) void k_wf_gemm(
        const float* __restrict__ A, const float* __restrict__ W,
        const float* __restrict__ bias, float* __restrict__ wf) {
    __shared__ float AsT[16][132];   // [k][m], stride 132 keeps 16B align, breaks conflicts
    __shared__ float WsT[16][68];    // [k][n]
    const int tid = threadIdx.x;
    const int tx = tid & 15, ty = tid >> 4;
    const int n0 = blockIdx.x * 64;
    const int m0 = blockIdx.y * 128;

    const int arow = tid >> 2;            // 0..63
    const int kq   = (tid & 3) << 2;      // 0,4,8,12

    const float* ga0 = A + (m0 + arow) * Cn + kq;
    const float* ga1 = ga0 + 64 * Cn;
    const float* gw  = W + (n0 + arow) * Cn + kq;

    float4 ra0 = *(const float4*)ga0;
    float4 ra1 = *(const float4*)ga1;
    float4 rw  = *(const float4*)gw;

    float acc[8][4];
    #pragma unroll
    for (int i = 0; i < 8; ++i)
        #pragma unroll
        for (int j = 0; j < 4; ++j) acc[i][j] = 0.f;

    for (int s = 0; s < 32; ++s) {
        __syncthreads();
        AsT[kq+0][arow]    = ra0.x; AsT[kq+1][arow]    = ra0.y;
        AsT[kq+2][arow]    = ra0.z; AsT[kq+3][arow]    = ra0.w;
        AsT[kq+0][arow+64] = ra1.x; AsT[kq+1][arow+64] = ra1.y;
        AsT[kq+2][arow+64] = ra1.z; AsT[kq+3][arow+64] = ra1.w;
        WsT[kq+0][arow]    = rw.x;  WsT[kq+1][arow]    = rw.y;
        WsT[kq+2][arow]    = rw.z;  WsT[kq+3][arow]    = rw.w;
        __syncthreads();
        if (s < 31) {
            ga0 += 16; ga1 += 16; gw += 16;
            ra0 = *(const float4*)ga0;
            ra1 = *(const float4*)ga1;
            rw  = *(const float4*)gw;
        }
        #pragma unroll
        for (int k = 0; k < 16; ++k) {
            float4 a0 = *(const float4*)&AsT[k][ty*8];
            float4 a1 = *(const float4*)&AsT[k][ty*8+4];
            float4 bb = *(const float4*)&WsT[k][tx*4];
            float a[8] = {a0.x,a0.y,a0.z,a0.w,a1.x,a1.y,a1.z,a1.w};
            float b[4] = {bb.x,bb.y,bb.z,bb.w};
            #pragma unroll
            for (int i = 0; i < 8; ++i)
                #pragma unroll
                for (int j = 0; j < 4; ++j)
                    acc[i][j] = fmaf(a[i], b[j], acc[i][j]);
        }
    }

    const float4 bv = *(const float4*)&bias[n0 + tx*4];
    #pragma unroll
    for (int i = 0; i < 8; ++i) {
        float4 o;
        o.x = acc[i][0] + bv.x; o.y = acc[i][1] + bv.y;
        o.z = acc[i][2] + bv.z; o.w = acc[i][3] + bv.w;
        *(float4*)&wf[(m0 + ty*8 + i) * Cn + n0 + tx*4] = o;
    }
}

// K2: scores[b][l][t] = sum_c tanh(wf[b,t,c] + pos[l,c]) * aw[c]
// (atten_b omitted: a constant shift cancels exactly in softmax)
// One wave per (b,t); 4 waves/block; grid (T/4, B).
__global__ __launch_bounds__(256) void k_scores(
        const float* __restrict__ wf, const float* __restrict__ pos,
        const float* __restrict__ aw, float* __restrict__ scores) {
    __shared__ float pos_lds[Ln * Cn];   // 51200 B
    const int tid = threadIdx.x;
    for (int i = tid * 4; i < Ln * Cn; i += 1024)
        *(float4*)&pos_lds[i] = *(const float4*)&pos[i];
    __syncthreads();

    const int lane = tid & 63;
    const int wv   = tid >> 6;
    const int t    = blockIdx.x * 4 + wv;
    const int b    = blockIdx.y;

    const float* wfp = wf + (b * Tn + t) * Cn;
    const float4 w0 = *(const float4*)&wfp[lane * 4];
    const float4 w1 = *(const float4*)&wfp[256 + lane * 4];
    const float4 u0 = *(const float4*)&aw[lane * 4];
    const float4 u1 = *(const float4*)&aw[256 + lane * 4];

    float r[Ln];
    #pragma unroll
    for (int l = 0; l < Ln; ++l) {
        const float4 p0 = *(const float4*)&pos_lds[l * Cn + lane * 4];
        const float4 p1 = *(const float4*)&pos_lds[l * Cn + 256 + lane * 4];
        float s;
        s  = tanh_fast(w0.x + p0.x) * u0.x;
        s += tanh_fast(w0.y + p0.y) * u0.y;
        s += tanh_fast(w0.z + p0.z) * u0.z;
        s += tanh_fast(w0.w + p0.w) * u0.w;
        s += tanh_fast(w1.x + p1.x) * u1.x;
        s += tanh_fast(w1.y + p1.y) * u1.y;
        s += tanh_fast(w1.z + p1.z) * u1.z;
        s += tanh_fast(w1.w + p1.w) * u1.w;
        r[l] = s;
    }
    #pragma unroll
    for (int l = 0; l < Ln; ++l) {
        float v = r[l];
        #pragma unroll
        for (int o = 32; o > 0; o >>= 1) v += __shfl_xor(v, o);
        if (lane == 0) scores[(b * Ln + l) * Tn + t] = v;
    }
}

// K3: softmax over t then pvam[b][l][c] = sum_t p[l][t] * wf[b][t][c]
// Block per (c-chunk of 64, b); grid (C/64, B); 256 threads (4 waves).
__global__ __launch_bounds__(256) void k_pvam(
        const float* __restrict__ wf, const float* __restrict__ scores,
        float* __restrict__ out) {
    __shared__ float sbuf[Ln * Tn];      // scores, later reused as cross-wave red buf
    __shared__ float pT[Tn][28];         // transposed softmax probs, 112B rows (16B aligned)
    const int tid = threadIdx.x;
    const int cx  = blockIdx.x;
    const int b   = blockIdx.y;

    for (int i = tid * 4; i < Ln * Tn; i += 1024)
        *(float4*)&sbuf[i] = *(const float4*)&scores[b * Ln * Tn + i];
    __syncthreads();

    const int lane = tid & 63;
    const int wv   = tid >> 6;

    for (int l = wv; l < Ln; l += 4) {
        float v0 = sbuf[l * Tn + lane];
        float v1 = sbuf[l * Tn + 64 + lane];
        float v2 = sbuf[l * Tn + 128 + lane];
        float v3 = sbuf[l * Tn + 192 + lane];
        float m = fmaxf(fmaxf(v0, v1), fmaxf(v2, v3));
        #pragma unroll
        for (int o = 32; o > 0; o >>= 1) m = fmaxf(m, __shfl_xor(m, o));
        float e0 = __expf(v0 - m), e1 = __expf(v1 - m);
        float e2 = __expf(v2 - m), e3 = __expf(v3 - m);
        float s = e0 + e1 + e2 + e3;
        #pragma unroll
        for (int o = 32; o > 0; o >>= 1) s += __shfl_xor(s, o);
        float rs = __builtin_amdgcn_rcpf(s);
        pT[lane][l]       = e0 * rs;
        pT[64 + lane][l]  = e1 * rs;
        pT[128 + lane][l] = e2 * rs;
        pT[192 + lane][l] = e3 * rs;
    }
    __syncthreads();

    const int c = cx * 64 + lane;
    float acc[Ln];
    #pragma unroll
    for (int l = 0; l < Ln; ++l) acc[l] = 0.f;

    const float* wfp = wf + (b * Tn + wv * 64) * Cn + c;
    for (int tt = 0; tt < 64; ++tt) {
        float w = wfp[tt * Cn];
        const float* pp = &pT[wv * 64 + tt][0];
        float p[Ln];
        *(float4*)&p[0]  = *(const float4*)&pp[0];
        *(float4*)&p[4]  = *(const float4*)&pp[4];
        *(float4*)&p[8]  = *(const float4*)&pp[8];
        *(float4*)&p[12] = *(const float4*)&pp[12];
        *(float4*)&p[16] = *(const float4*)&pp[16];
        *(float4*)&p[20] = *(const float4*)&pp[20];
        p[24] = pp[24];
        #pragma unroll
        for (int l = 0; l < Ln; ++l) acc[l] = fmaf(p[l], w, acc[l]);
    }

    // cross-wave reduction via sbuf (scores no longer needed)
    #pragma unroll
    for (int l = 0; l < Ln; ++l)
        sbuf[(wv * Ln + l) * 64 + lane] = acc[l];
    __syncthreads();
    for (int idx = tid; idx < Ln * 64; idx += 256) {
        int l = idx >> 6, cc = idx & 63;
        float v = sbuf[(0 * Ln + l) * 64 + cc] + sbuf[(1 * Ln + l) * 64 + cc]
                + sbuf[(2 * Ln + l) * 64 + cc] + sbuf[(3 * Ln + l) * 64 + cc];
        out[(b * Ln + l) * Cn + cx * 64 + cc] = v;
    }
}

extern "C" void kernel_launch(void* const* d_in, const int* in_sizes, int n_in,
                              void* d_out, int out_size, void* d_ws, size_t ws_size,
                              hipStream_t stream) {
    const float* A    = (const float*)d_in[0];  // word_features (B,T,C)
    const float* W    = (const float*)d_in[1];  // word_fc_w (d,c)
    const float* bias = (const float*)d_in[2];  // word_fc_b (C)
    const float* pos  = (const float*)d_in[3];  // pos_emb (L,C)
    const float* aw   = (const float*)d_in[4];  // atten_w (C)
    // d_in[5] atten_b: constant shift, cancels in softmax

    float* wf     = (float*)d_ws;                       // 8192*512 fp32 = 16.8 MB
    float* scores = (float*)d_ws + (Bn * Tn * Cn);      // 32*25*256 fp32 = 0.8 MB
    float* out    = (float*)d_out;

    k_wf_gemm<<<dim3(Cn / 64, (Bn * Tn) / 128), 256, 0, stream>>>(A, W, bias, wf);
    k_scores<<<dim3(Tn / 4, Bn), 256, 0, stream>>>(wf, pos, aw, scores);
    k_pvam<<<dim3(Cn / 64, Bn), 256, 0, stream>>>(wf, scores, out);
}

// Round 2
// 158.557 us; speedup vs baseline: 1.2021x; 1.2021x over previous
//
#include <hip/hip_runtime.h>

#define Bn 32
#define Tn 256
#define Cn 512
#define Ln 25
#define K2n 1024   // split K: (hi,lo) interleaved

typedef __attribute__((ext_vector_type(8))) short sh8;
typedef __attribute__((ext_vector_type(4))) float f32x4;

__device__ __forceinline__ unsigned short f2bf(float f) {
    unsigned u = __float_as_uint(f);
    u += 0x7FFF + ((u >> 16) & 1);          // RNE
    return (unsigned short)(u >> 16);
}
__device__ __forceinline__ float bf2f(unsigned short b) {
    return __uint_as_float(((unsigned)b) << 16);
}

__device__ __forceinline__ float tanh_fast(float x) {
    float e = __expf(x + x);
    float r = __builtin_amdgcn_rcpf(e + 1.0f);
    return fmaf(-2.0f, r, 1.0f);
}

// K0: A (8192x512 fp32) -> A2 (8192x1024 bf16, interleaved hi/lo)
//     W (512x512 fp32)  -> W2 (512x1024 bf16, each w duplicated)
#define NA_QUAD (Bn * Tn * Cn / 4)          // 1048576
#define NW_QUAD (Cn * Cn / 4)               // 65536
__global__ __launch_bounds__(256) void k_convert(
        const float* __restrict__ A, const float* __restrict__ W,
        unsigned short* __restrict__ A2, unsigned short* __restrict__ W2) {
    int idx = blockIdx.x * 256 + threadIdx.x;
    if (idx < NA_QUAD) {
        int m = idx >> 7, kq = (idx & 127) << 2;
        float4 a = *(const float4*)&A[m * Cn + kq];
        sh8 o;
        float v[4] = {a.x, a.y, a.z, a.w};
        #pragma unroll
        for (int i = 0; i < 4; ++i) {
            unsigned short hi = f2bf(v[i]);
            unsigned short lo = f2bf(v[i] - bf2f(hi));
            o[2 * i] = (short)hi; o[2 * i + 1] = (short)lo;
        }
        *(sh8*)&A2[(size_t)m * K2n + kq * 2] = o;
    } else {
        int j = idx - NA_QUAD;
        int n = j >> 7, kq = (j & 127) << 2;
        float4 w = *(const float4*)&W[n * Cn + kq];
        sh8 o;
        float v[4] = {w.x, w.y, w.z, w.w};
        #pragma unroll
        for (int i = 0; i < 4; ++i) {
            short b = (short)f2bf(v[i]);
            o[2 * i] = b; o[2 * i + 1] = b;
        }
        *(sh8*)&W2[(size_t)n * K2n + kq * 2] = o;
    }
}

// K1: wf[m][n] = sum_k2 A2[m][k2]*W2[n][k2] + bias[n]   (bf16 MFMA)
// Tile 128(m) x 64(n), BK=32, 256 thr = 4 waves in 2x2, wave-tile 64x32.
#define BM 128
#define BN 64
#define BK 32
__global__ __launch_bounds__(256) void k_gemm(
        const unsigned short* __restrict__ A2, const unsigned short* __restrict__ W2,
        const float* __restrict__ bias, float* __restrict__ wf) {
    __shared__ unsigned short As[BM * BK];   // 8 KB
    __shared__ unsigned short Ws[BN * BK];   // 4 KB
    const int tid  = threadIdx.x;
    const int lane = tid & 63;
    const int wv   = tid >> 6;
    const int m0 = blockIdx.y * BM;
    const int n0 = blockIdx.x * BN;
    const int wm = (wv >> 1) * 64;           // wave m-offset in tile
    const int wn = (wv & 1) * 32;            // wave n-offset in tile
    const int r = lane & 15, q = lane >> 4;

    // staging descriptors (chunk = 16B = 8 bf16)
    // A: 512 chunks, wave wv pass p handles chunks (p*4+wv)*64 + lane
    const int ciA0 = (0 * 4 + wv) * 64 + lane;
    const int ciA1 = (1 * 4 + wv) * 64 + lane;
    const int ciW  = wv * 64 + lane;
    const unsigned short* gA0 = A2 + (size_t)(m0 + (ciA0 >> 2)) * K2n + (ciA0 & 3) * 8;
    const unsigned short* gA1 = A2 + (size_t)(m0 + (ciA1 >> 2)) * K2n + (ciA1 & 3) * 8;
    const unsigned short* gW  = W2 + (size_t)(n0 + (ciW  >> 2)) * K2n + (ciW  & 3) * 8;
    unsigned short* lA0 = As + (0 * 4 + wv) * 512;   // wave-uniform LDS bases
    unsigned short* lA1 = As + (1 * 4 + wv) * 512;
    unsigned short* lW  = Ws + wv * 512;

    f32x4 acc[4][2];
    #pragma unroll
    for (int mi = 0; mi < 4; ++mi)
        #pragma unroll
        for (int ni = 0; ni < 2; ++ni) acc[mi][ni] = (f32x4){0.f, 0.f, 0.f, 0.f};

    for (int kt = 0; kt < K2n / BK; ++kt) {
        __syncthreads();
        __builtin_amdgcn_global_load_lds(
            (const __attribute__((address_space(1))) unsigned int*)gA0,
            (__attribute__((address_space(3))) unsigned int*)lA0, 16, 0, 0);
        __builtin_amdgcn_global_load_lds(
            (const __attribute__((address_space(1))) unsigned int*)gA1,
            (__attribute__((address_space(3))) unsigned int*)lA1, 16, 0, 0);
        __builtin_amdgcn_global_load_lds(
            (const __attribute__((address_space(1))) unsigned int*)gW,
            (__attribute__((address_space(3))) unsigned int*)lW, 16, 0, 0);
        gA0 += BK; gA1 += BK; gW += BK;
        __syncthreads();

        sh8 af[4], bfr[2];
        #pragma unroll
        for (int mi = 0; mi < 4; ++mi)
            af[mi] = *(const sh8*)&As[(wm + mi * 16 + r) * BK + q * 8];
        #pragma unroll
        for (int ni = 0; ni < 2; ++ni)
            bfr[ni] = *(const sh8*)&Ws[(wn + ni * 16 + r) * BK + q * 8];
        #pragma unroll
        for (int mi = 0; mi < 4; ++mi)
            #pragma unroll
            for (int ni = 0; ni < 2; ++ni)
                acc[mi][ni] = __builtin_amdgcn_mfma_f32_16x16x32_bf16(
                    af[mi], bfr[ni], acc[mi][ni], 0, 0, 0);
    }

    #pragma unroll
    for (int ni = 0; ni < 2; ++ni) {
        const float bv = bias[n0 + wn + ni * 16 + r];
        #pragma unroll
        for (int mi = 0; mi < 4; ++mi)
            #pragma unroll
            for (int reg = 0; reg < 4; ++reg) {
                int row = m0 + wm + mi * 16 + q * 4 + reg;
                int col = n0 + wn + ni * 16 + r;
                wf[(size_t)row * Cn + col] = acc[mi][ni][reg] + bv;
            }
    }
}

// K2: scores[b][l][t] = sum_c tanh(wf[b,t,c] + pos[l,c]) * aw[c]
__global__ __launch_bounds__(256) void k_scores(
        const float* __restrict__ wf, const float* __restrict__ pos,
        const float* __restrict__ aw, float* __restrict__ scores) {
    __shared__ float pos_lds[Ln * Cn];
    const int tid = threadIdx.x;
    for (int i = tid * 4; i < Ln * Cn; i += 1024)
        *(float4*)&pos_lds[i] = *(const float4*)&pos[i];
    __syncthreads();

    const int lane = tid & 63;
    const int wv   = tid >> 6;
    const int t    = blockIdx.x * 4 + wv;
    const int b    = blockIdx.y;

    const float* wfp = wf + (b * Tn + t) * Cn;
    const float4 w0 = *(const float4*)&wfp[lane * 4];
    const float4 w1 = *(const float4*)&wfp[256 + lane * 4];
    const float4 u0 = *(const float4*)&aw[lane * 4];
    const float4 u1 = *(const float4*)&aw[256 + lane * 4];

    float rr[Ln];
    #pragma unroll
    for (int l = 0; l < Ln; ++l) {
        const float4 p0 = *(const float4*)&pos_lds[l * Cn + lane * 4];
        const float4 p1 = *(const float4*)&pos_lds[l * Cn + 256 + lane * 4];
        float s;
        s  = tanh_fast(w0.x + p0.x) * u0.x;
        s += tanh_fast(w0.y + p0.y) * u0.y;
        s += tanh_fast(w0.z + p0.z) * u0.z;
        s += tanh_fast(w0.w + p0.w) * u0.w;
        s += tanh_fast(w1.x + p1.x) * u1.x;
        s += tanh_fast(w1.y + p1.y) * u1.y;
        s += tanh_fast(w1.z + p1.z) * u1.z;
        s += tanh_fast(w1.w + p1.w) * u1.w;
        rr[l] = s;
    }
    #pragma unroll
    for (int l = 0; l < Ln; ++l) {
        float v = rr[l];
        #pragma unroll
        for (int o = 32; o > 0; o >>= 1) v += __shfl_xor(v, o);
        if (lane == 0) scores[(b * Ln + l) * Tn + t] = v;
    }
}

// K3: softmax over t; out[b][l][c] = sum_t p[l][t] * wf[b][t][c]
// 512 threads (8 waves), block per (c-chunk of 64, b).
__global__ __launch_bounds__(512) void k_pvam(
        const float* __restrict__ wf, const float* __restrict__ scores,
        float* __restrict__ out) {
    __shared__ float sbuf[Ln * Tn];          // 25.6 KB
    __shared__ float pT[Tn][28];             // 28.7 KB
    __shared__ float red[8 * Ln * 64];       // 51.2 KB
    const int tid = threadIdx.x;
    const int cx  = blockIdx.x;
    const int b   = blockIdx.y;

    for (int i = tid * 4; i < Ln * Tn; i += 2048)
        *(float4*)&sbuf[i] = *(const float4*)&scores[b * Ln * Tn + i];
    __syncthreads();

    const int lane = tid & 63;
    const int wv   = tid >> 6;

    for (int l = wv; l < Ln; l += 8) {
        float v0 = sbuf[l * Tn + lane];
        float v1 = sbuf[l * Tn + 64 + lane];
        float v2 = sbuf[l * Tn + 128 + lane];
        float v3 = sbuf[l * Tn + 192 + lane];
        float m = fmaxf(fmaxf(v0, v1), fmaxf(v2, v3));
        #pragma unroll
        for (int o = 32; o > 0; o >>= 1) m = fmaxf(m, __shfl_xor(m, o));
        float e0 = __expf(v0 - m), e1 = __expf(v1 - m);
        float e2 = __expf(v2 - m), e3 = __expf(v3 - m);
        float s = e0 + e1 + e2 + e3;
        #pragma unroll
        for (int o = 32; o > 0; o >>= 1) s += __shfl_xor(s, o);
        float rs = __builtin_amdgcn_rcpf(s);
        pT[lane][l]       = e0 * rs;
        pT[64 + lane][l]  = e1 * rs;
        pT[128 + lane][l] = e2 * rs;
        pT[192 + lane][l] = e3 * rs;
    }
    __syncthreads();

    const int c = cx * 64 + lane;
    float acc[Ln];
    #pragma unroll
    for (int l = 0; l < Ln; ++l) acc[l] = 0.f;

    const float* wfp = wf + (b * Tn + wv * 32) * Cn + c;
    for (int tt = 0; tt < 32; ++tt) {
        float w = wfp[tt * Cn];
        const float* pp = &pT[wv * 32 + tt][0];
        float p[Ln];
        *(float4*)&p[0]  = *(const float4*)&pp[0];
        *(float4*)&p[4]  = *(const float4*)&pp[4];
        *(float4*)&p[8]  = *(const float4*)&pp[8];
        *(float4*)&p[12] = *(const float4*)&pp[12];
        *(float4*)&p[16] = *(const float4*)&pp[16];
        *(float4*)&p[20] = *(const float4*)&pp[20];
        p[24] = pp[24];
        #pragma unroll
        for (int l = 0; l < Ln; ++l) acc[l] = fmaf(p[l], w, acc[l]);
    }

    #pragma unroll
    for (int l = 0; l < Ln; ++l)
        red[(wv * Ln + l) * 64 + lane] = acc[l];
    __syncthreads();
    for (int idx = tid; idx < Ln * 64; idx += 512) {
        int l = idx >> 6, cc = idx & 63;
        float v = 0.f;
        #pragma unroll
        for (int w = 0; w < 8; ++w) v += red[(w * Ln + l) * 64 + cc];
        out[(b * Ln + l) * Cn + cx * 64 + cc] = v;
    }
}

extern "C" void kernel_launch(void* const* d_in, const int* in_sizes, int n_in,
                              void* d_out, int out_size, void* d_ws, size_t ws_size,
                              hipStream_t stream) {
    const float* A    = (const float*)d_in[0];
    const float* W    = (const float*)d_in[1];
    const float* bias = (const float*)d_in[2];
    const float* pos  = (const float*)d_in[3];
    const float* aw   = (const float*)d_in[4];

    char* ws = (char*)d_ws;
    float*          wf     = (float*)ws;                                   // 16.8 MB
    float*          scores = (float*)(ws + (size_t)Bn * Tn * Cn * 4);      // 0.8 MB
    unsigned short* A2     = (unsigned short*)(ws + 17620992ull);          // 16.8 MB
    unsigned short* W2     = (unsigned short*)(ws + 17620992ull + 16777216ull); // 1 MB
    float* out = (float*)d_out;

    k_convert<<<(NA_QUAD + NW_QUAD) / 256, 256, 0, stream>>>(A, W, A2, W2);
    k_gemm<<<dim3(Cn / BN, (Bn * Tn) / BM), 256, 0, stream>>>(A2, W2, bias, wf);
    k_scores<<<dim3(Tn / 4, Bn), 256, 0, stream>>>(wf, pos, aw, scores);
    k_pvam<<<dim3(Cn / 64, Bn), 512, 0, stream>>>(wf, scores, out);
}

// Round 3
// 136.000 us; speedup vs baseline: 1.4015x; 1.1659x over previous
//
#include <hip/hip_runtime.h>

#define Bn 32
#define Tn 256
#define Cn 512
#define Ln 25
#define K2n 1024   // split K: (hi,lo) interleaved

typedef __attribute__((ext_vector_type(8))) short sh8;
typedef __attribute__((ext_vector_type(4))) float f32x4;

#define SCALE2LOG2E 2.885390081777927f   // 2*log2(e)

#if __has_builtin(__builtin_amdgcn_exp2f)
#define EXP2(x) __builtin_amdgcn_exp2f(x)
#else
#define EXP2(x) __expf(0.69314718056f * (x))
#endif

// sum across 16-lane groups, all on VALU pipe (no LDS): xor1,xor2,xor7,xor15 pairings
#define DPP_ADD(v, ctrl) \
    ((v) + __int_as_float(__builtin_amdgcn_update_dpp(0, __float_as_int(v), ctrl, 0xf, 0xf, true)))

__device__ __forceinline__ unsigned short f2bf(float f) {
    unsigned u = __float_as_uint(f);
    u += 0x7FFF + ((u >> 16) & 1);          // RNE
    return (unsigned short)(u >> 16);
}
__device__ __forceinline__ float bf2f(unsigned short b) {
    return __uint_as_float(((unsigned)b) << 16);
}

// K0: A (8192x512 fp32) -> A2 (8192x1024 bf16, interleaved hi/lo)
//     W (512x512 fp32)  -> W2 (512x1024 bf16, each w duplicated)
#define NA_QUAD (Bn * Tn * Cn / 4)          // 1048576
#define NW_QUAD (Cn * Cn / 4)               // 65536
__global__ __launch_bounds__(256) void k_convert(
        const float* __restrict__ A, const float* __restrict__ W,
        unsigned short* __restrict__ A2, unsigned short* __restrict__ W2) {
    int idx = blockIdx.x * 256 + threadIdx.x;
    if (idx < NA_QUAD) {
        int m = idx >> 7, kq = (idx & 127) << 2;
        float4 a = *(const float4*)&A[m * Cn + kq];
        sh8 o;
        float v[4] = {a.x, a.y, a.z, a.w};
        #pragma unroll
        for (int i = 0; i < 4; ++i) {
            unsigned short hi = f2bf(v[i]);
            unsigned short lo = f2bf(v[i] - bf2f(hi));
            o[2 * i] = (short)hi; o[2 * i + 1] = (short)lo;
        }
        *(sh8*)&A2[(size_t)m * K2n + kq * 2] = o;
    } else {
        int j = idx - NA_QUAD;
        int n = j >> 7, kq = (j & 127) << 2;
        float4 w = *(const float4*)&W[n * Cn + kq];
        sh8 o;
        float v[4] = {w.x, w.y, w.z, w.w};
        #pragma unroll
        for (int i = 0; i < 4; ++i) {
            short b = (short)f2bf(v[i]);
            o[2 * i] = b; o[2 * i + 1] = b;
        }
        *(sh8*)&W2[(size_t)n * K2n + kq * 2] = o;
    }
}

// K1: wf[m][n] = sum_k2 A2[m][k2]*W2[n][k2] + bias[n]   (bf16 MFMA)
// Tile 128x64, BK=64 shorts, 4 waves in 2x2. XOR-swizzled LDS (chunk = 16B):
// logical chunk lk of row stored at phys pk = lk ^ (row&7) -> frag ds_read_b128
// spreads 8 consecutive rows over all 32 banks (2-way residual = free).
#define BM 128
#define BN 64
#define BKg 64
__global__ __launch_bounds__(256) void k_gemm(
        const unsigned short* __restrict__ A2, const unsigned short* __restrict__ W2,
        const float* __restrict__ bias, float* __restrict__ wf) {
    __shared__ unsigned short As[BM * BKg];   // 16 KB
    __shared__ unsigned short Ws[BN * BKg];   // 8 KB
    const int tid  = threadIdx.x;
    const int lane = tid & 63;
    const int wv   = tid >> 6;
    const int m0 = blockIdx.y * BM;
    const int n0 = blockIdx.x * BN;
    const int wm = (wv >> 1) * 64;
    const int wn = (wv & 1) * 32;
    const int r = lane & 15, q = lane >> 4;

    // staging sources: phys slot p = rr*256 + tid; swizzled global chunk
    const unsigned short* gA[4];
    const unsigned short* gW[2];
    #pragma unroll
    for (int rr = 0; rr < 4; ++rr) {
        int p = rr * 256 + tid;
        int row = p >> 3, pk = p & 7;
        int lk = pk ^ (row & 7);
        gA[rr] = A2 + (size_t)(m0 + row) * K2n + lk * 8;
    }
    #pragma unroll
    for (int rr = 0; rr < 2; ++rr) {
        int p = rr * 256 + tid;
        int row = p >> 3, pk = p & 7;
        int lk = pk ^ (row & 7);
        gW[rr] = W2 + (size_t)(n0 + row) * K2n + lk * 8;
    }

    f32x4 acc[4][2];
    #pragma unroll
    for (int mi = 0; mi < 4; ++mi)
        #pragma unroll
        for (int ni = 0; ni < 2; ++ni) acc[mi][ni] = (f32x4){0.f, 0.f, 0.f, 0.f};

    for (int kt = 0; kt < K2n / BKg; ++kt) {
        __syncthreads();
        #pragma unroll
        for (int rr = 0; rr < 4; ++rr) {
            __builtin_amdgcn_global_load_lds(
                (const __attribute__((address_space(1))) unsigned int*)gA[rr],
                (__attribute__((address_space(3))) unsigned int*)(As + (rr * 256 + wv * 64) * 8),
                16, 0, 0);
            gA[rr] += BKg;
        }
        #pragma unroll
        for (int rr = 0; rr < 2; ++rr) {
            __builtin_amdgcn_global_load_lds(
                (const __attribute__((address_space(1))) unsigned int*)gW[rr],
                (__attribute__((address_space(3))) unsigned int*)(Ws + (rr * 256 + wv * 64) * 8),
                16, 0, 0);
            gW[rr] += BKg;
        }
        __syncthreads();

        sh8 af[4][2], bfr[2][2];
        #pragma unroll
        for (int mi = 0; mi < 4; ++mi)
            #pragma unroll
            for (int kk = 0; kk < 2; ++kk) {
                int row = wm + mi * 16 + r;
                int phys = (kk * 4 + q) ^ (r & 7);
                af[mi][kk] = *(const sh8*)&As[row * BKg + phys * 8];
            }
        #pragma unroll
        for (int ni = 0; ni < 2; ++ni)
            #pragma unroll
            for (int kk = 0; kk < 2; ++kk) {
                int row = wn + ni * 16 + r;
                int phys = (kk * 4 + q) ^ (r & 7);
                bfr[ni][kk] = *(const sh8*)&Ws[row * BKg + phys * 8];
            }
        #pragma unroll
        for (int kk = 0; kk < 2; ++kk)
            #pragma unroll
            for (int mi = 0; mi < 4; ++mi)
                #pragma unroll
                for (int ni = 0; ni < 2; ++ni)
                    acc[mi][ni] = __builtin_amdgcn_mfma_f32_16x16x32_bf16(
                        af[mi][kk], bfr[ni][kk], acc[mi][ni], 0, 0, 0);
    }

    #pragma unroll
    for (int ni = 0; ni < 2; ++ni) {
        const float bv = bias[n0 + wn + ni * 16 + r];
        #pragma unroll
        for (int mi = 0; mi < 4; ++mi)
            #pragma unroll
            for (int reg = 0; reg < 4; ++reg) {
                int row = m0 + wm + mi * 16 + q * 4 + reg;
                int col = n0 + wn + ni * 16 + r;
                wf[(size_t)row * Cn + col] = acc[mi][ni][reg] + bv;
            }
    }
}

// K2: scores. tanh(x)*u summed over c == sum(u) - 2*sum(u * 1/(1+exp2(SCALE*x))).
// 8 waves/block (one t each); per-16-lane DPP reduce; 4 partial planes to global.
__global__ __launch_bounds__(512) void k_scores(
        const float* __restrict__ wf, const float* __restrict__ pos,
        const float* __restrict__ aw, float* __restrict__ scores4) {
    __shared__ float pos2[Ln * Cn];          // 51.2 KB, pre-scaled by 2log2e
    const int tid = threadIdx.x;
    for (int i = tid * 4; i < Ln * Cn; i += 2048) {
        float4 p = *(const float4*)&pos[i];
        p.x *= SCALE2LOG2E; p.y *= SCALE2LOG2E; p.z *= SCALE2LOG2E; p.w *= SCALE2LOG2E;
        *(float4*)&pos2[i] = p;
    }
    __syncthreads();

    const int lane = tid & 63;
    const int wv   = tid >> 6;
    const int t    = blockIdx.x * 8 + wv;
    const int b    = blockIdx.y;

    const float* wfp = wf + (b * Tn + t) * Cn;
    float4 w0 = *(const float4*)&wfp[lane * 4];
    float4 w1 = *(const float4*)&wfp[256 + lane * 4];
    w0.x *= SCALE2LOG2E; w0.y *= SCALE2LOG2E; w0.z *= SCALE2LOG2E; w0.w *= SCALE2LOG2E;
    w1.x *= SCALE2LOG2E; w1.y *= SCALE2LOG2E; w1.z *= SCALE2LOG2E; w1.w *= SCALE2LOG2E;
    const float4 a0 = *(const float4*)&aw[lane * 4];
    const float4 a1 = *(const float4*)&aw[256 + lane * 4];
    const float U = a0.x + a0.y + a0.z + a0.w + a1.x + a1.y + a1.z + a1.w;
    float4 u0, u1;   // -2*aw
    u0.x = -2.f * a0.x; u0.y = -2.f * a0.y; u0.z = -2.f * a0.z; u0.w = -2.f * a0.w;
    u1.x = -2.f * a1.x; u1.y = -2.f * a1.y; u1.z = -2.f * a1.z; u1.w = -2.f * a1.w;

    float* sp = scores4 + ((lane >> 4) * (Bn * Ln * Tn)) + (b * Ln) * Tn + t;
    const bool writer = ((lane & 15) == 0);

    #pragma unroll
    for (int l = 0; l < Ln; ++l) {
        const float4 p0 = *(const float4*)&pos2[l * Cn + lane * 4];
        const float4 p1 = *(const float4*)&pos2[l * Cn + 256 + lane * 4];
        float s = U;
        s = fmaf(u0.x, __builtin_amdgcn_rcpf(1.f + EXP2(w0.x + p0.x)), s);
        s = fmaf(u0.y, __builtin_amdgcn_rcpf(1.f + EXP2(w0.y + p0.y)), s);
        s = fmaf(u0.z, __builtin_amdgcn_rcpf(1.f + EXP2(w0.z + p0.z)), s);
        s = fmaf(u0.w, __builtin_amdgcn_rcpf(1.f + EXP2(w0.w + p0.w)), s);
        s = fmaf(u1.x, __builtin_amdgcn_rcpf(1.f + EXP2(w1.x + p1.x)), s);
        s = fmaf(u1.y, __builtin_amdgcn_rcpf(1.f + EXP2(w1.y + p1.y)), s);
        s = fmaf(u1.z, __builtin_amdgcn_rcpf(1.f + EXP2(w1.z + p1.z)), s);
        s = fmaf(u1.w, __builtin_amdgcn_rcpf(1.f + EXP2(w1.w + p1.w)), s);
        s = DPP_ADD(s, 0xB1);    // xor 1 (quad_perm 1,0,3,2)
        s = DPP_ADD(s, 0x4E);    // xor 2 (quad_perm 2,3,0,1)
        s = DPP_ADD(s, 0x141);   // row_half_mirror (xor 7)
        s = DPP_ADD(s, 0x140);   // row_mirror (xor 15)
        if (writer) sp[l * Tn] = s;
    }
}

// K3: softmax over t; out[b][l][c] = sum_t p[l][t] * wf[b][t][c]
// 512 threads (8 waves), block per (c-chunk of 64, b). sbuf/red aliased: 80KB -> 2 blk/CU.
__global__ __launch_bounds__(512) void k_pvam(
        const float* __restrict__ wf, const float* __restrict__ scores4,
        float* __restrict__ out) {
    __shared__ float buf[8 * Ln * 64];       // 51.2 KB: scores staging, then reduction
    __shared__ float pT[Tn][28];             // 28.7 KB
    const int tid = threadIdx.x;
    const int cx  = blockIdx.x;
    const int b   = blockIdx.y;

    const float* sc = scores4 + b * Ln * Tn;
    const int PL = Bn * Ln * Tn;
    for (int i = tid * 4; i < Ln * Tn; i += 2048) {
        float4 s0 = *(const float4*)&sc[i];
        float4 s1 = *(const float4*)&sc[PL + i];
        float4 s2 = *(const float4*)&sc[2 * PL + i];
        float4 s3 = *(const float4*)&sc[3 * PL + i];
        float4 v;
        v.x = (s0.x + s1.x) + (s2.x + s3.x);
        v.y = (s0.y + s1.y) + (s2.y + s3.y);
        v.z = (s0.z + s1.z) + (s2.z + s3.z);
        v.w = (s0.w + s1.w) + (s2.w + s3.w);
        *(float4*)&buf[i] = v;
    }
    __syncthreads();

    const int lane = tid & 63;
    const int wv   = tid >> 6;

    for (int l = wv; l < Ln; l += 8) {
        float v0 = buf[l * Tn + lane];
        float v1 = buf[l * Tn + 64 + lane];
        float v2 = buf[l * Tn + 128 + lane];
        float v3 = buf[l * Tn + 192 + lane];
        float m = fmaxf(fmaxf(v0, v1), fmaxf(v2, v3));
        #pragma unroll
        for (int o = 32; o > 0; o >>= 1) m = fmaxf(m, __shfl_xor(m, o));
        float e0 = __expf(v0 - m), e1 = __expf(v1 - m);
        float e2 = __expf(v2 - m), e3 = __expf(v3 - m);
        float s = e0 + e1 + e2 + e3;
        #pragma unroll
        for (int o = 32; o > 0; o >>= 1) s += __shfl_xor(s, o);
        float rs = __builtin_amdgcn_rcpf(s);
        pT[lane][l]       = e0 * rs;
        pT[64 + lane][l]  = e1 * rs;
        pT[128 + lane][l] = e2 * rs;
        pT[192 + lane][l] = e3 * rs;
    }
    __syncthreads();

    const int c = cx * 64 + lane;
    float acc[Ln];
    #pragma unroll
    for (int l = 0; l < Ln; ++l) acc[l] = 0.f;

    const float* wfp = wf + (b * Tn + wv * 32) * Cn + c;
    for (int tt = 0; tt < 32; ++tt) {
        float w = wfp[tt * Cn];
        const float* pp = &pT[wv * 32 + tt][0];
        float p[Ln];
        *(float4*)&p[0]  = *(const float4*)&pp[0];
        *(float4*)&p[4]  = *(const float4*)&pp[4];
        *(float4*)&p[8]  = *(const float4*)&pp[8];
        *(float4*)&p[12] = *(const float4*)&pp[12];
        *(float4*)&p[16] = *(const float4*)&pp[16];
        *(float4*)&p[20] = *(const float4*)&pp[20];
        p[24] = pp[24];
        #pragma unroll
        for (int l = 0; l < Ln; ++l) acc[l] = fmaf(p[l], w, acc[l]);
    }

    __syncthreads();   // buf reuse: staging reads done long ago, but be safe
    #pragma unroll
    for (int l = 0; l < Ln; ++l)
        buf[(wv * Ln + l) * 64 + lane] = acc[l];
    __syncthreads();
    for (int idx = tid; idx < Ln * 64; idx += 512) {
        int l = idx >> 6, cc = idx & 63;
        float v = 0.f;
        #pragma unroll
        for (int w = 0; w < 8; ++w) v += buf[(w * Ln + l) * 64 + cc];
        out[(b * Ln + l) * Cn + cx * 64 + cc] = v;
    }
}

extern "C" void kernel_launch(void* const* d_in, const int* in_sizes, int n_in,
                              void* d_out, int out_size, void* d_ws, size_t ws_size,
                              hipStream_t stream) {
    const float* A    = (const float*)d_in[0];
    const float* W    = (const float*)d_in[1];
    const float* bias = (const float*)d_in[2];
    const float* pos  = (const float*)d_in[3];
    const float* aw   = (const float*)d_in[4];

    char* ws = (char*)d_ws;
    float*          wf      = (float*)ws;                          // 16.78 MB
    float*          scores4 = (float*)(ws + 16777216ull);          // 4 planes, 3.28 MB
    unsigned short* A2      = (unsigned short*)(ws + 20054016ull); // 16.78 MB
    unsigned short* W2      = (unsigned short*)(ws + 36831232ull); // 1 MB
    float* out = (float*)d_out;

    k_convert<<<(NA_QUAD + NW_QUAD) / 256, 256, 0, stream>>>(A, W, A2, W2);
    k_gemm<<<dim3(Cn / BN, (Bn * Tn) / BM), 256, 0, stream>>>(A2, W2, bias, wf);
    k_scores<<<dim3(Tn / 8, Bn), 512, 0, stream>>>(wf, pos, aw, scores4);
    k_pvam<<<dim3(Cn / 64, Bn), 512, 0, stream>>>(wf, scores4, out);
}